// Round 5
// baseline (58.784 us; speedup 1.0000x reference)
//
#include <hip/hip_runtime.h>

#define SQ 1024
#define HH 16
#define DK 4
#define EE 64

// R5 PROBE: identical kernels to R4, but each launched TWICE (idempotent).
// dur5 - dur4 = (qattn + proj) marginal cost; 2*dur4 - dur5 = fixed base.
// This decomposes the invariant ~32us into harness/launch floor vs kernel
// time, which three rounds of compute-side changes could not move.

__global__ __launch_bounds__(512) void qattn_kernel(
    const float* __restrict__ x, const float* __restrict__ theta,
    float* __restrict__ y) {
  const int tid = threadIdx.x;
  const int qtile = blockIdx.x & 3;    // 4 query tiles of 256
  const int bh = blockIdx.x >> 2;      // 0..63
  const int h = bh & (HH - 1);
  const int b = bh >> 4;

  // Chunk-skewed key store: chunk c starts at c*516 floats (bank offset 4c)
  // so the 8 distinct per-wave broadcast addresses hit distinct bank quads.
  __shared__ float kvf[8][516];

  const float4 th = *reinterpret_cast<const float4*>(theta);
  const float4 ct = make_float4(__cosf(th.x), __cosf(th.y),
                                __cosf(th.z), __cosf(th.w));

  // Stage all 1024 proj keys: x[b, t, h*4 + d] is a contiguous float4 per t.
  const float* xb = x + ((size_t)b * SQ) * EE + h * DK;
#pragma unroll
  for (int k = 0; k < 2; ++k) {
    const int t = tid + k * 512;
    const float4 v = *reinterpret_cast<const float4*>(xb + (size_t)t * EE);
    const float4 p = make_float4(__cosf(v.x) * ct.x, __cosf(v.y) * ct.y,
                                 __cosf(v.z) * ct.z, __cosf(v.w) * ct.w);
    *reinterpret_cast<float4*>(&kvf[t >> 7][(t & 127) * 4]) = p;
  }
  __syncthreads();

  const int c = tid & 7;               // key chunk 0..7 (128 keys each)
  const int qg = tid >> 3;             // query group 0..63 (4 queries each)
  const int q0 = qtile * 256 + qg * 4;

  // Load 4 query rows, pre-scaled by 0.5*log2(e) so inner loop is
  // fma-dot + v_exp_f32 (exp2) + fma-accum. |score|<=2 -> no max subtract.
  const float sc = 0.5f * 1.4426950408889634f;
  float4 qs[4];
#pragma unroll
  for (int i = 0; i < 4; ++i) {
    const int q = q0 + i;
    const float4 v =
        *reinterpret_cast<const float4*>(&kvf[q >> 7][(q & 127) * 4]);
    qs[i] = make_float4(v.x * sc, v.y * sc, v.z * sc, v.w * sc);
  }

  float den[4] = {0.f, 0.f, 0.f, 0.f};
  float4 num[4] = {{0.f, 0.f, 0.f, 0.f}, {0.f, 0.f, 0.f, 0.f},
                   {0.f, 0.f, 0.f, 0.f}, {0.f, 0.f, 0.f, 0.f}};
  const float* kc = kvf[c];
#pragma unroll 2
  for (int t = 0; t < 128; ++t) {
    const float4 kk = *reinterpret_cast<const float4*>(&kc[t * 4]);
#pragma unroll
    for (int i = 0; i < 4; ++i) {
      const float s = qs[i].x * kk.x + qs[i].y * kk.y +
                      qs[i].z * kk.z + qs[i].w * kk.w;
      const float e = __builtin_amdgcn_exp2f(s);
      den[i] += e;
      num[i].x += e * kk.x; num[i].y += e * kk.y;
      num[i].z += e * kk.z; num[i].w += e * kk.w;
    }
  }

  // Reduce the 8 chunk lanes (lane bits 0-2) for all 20 accumulators.
#pragma unroll
  for (int m = 1; m <= 4; m <<= 1) {
#pragma unroll
    for (int i = 0; i < 4; ++i) {
      den[i] += __shfl_xor(den[i], m);
      num[i].x += __shfl_xor(num[i].x, m);
      num[i].y += __shfl_xor(num[i].y, m);
      num[i].z += __shfl_xor(num[i].z, m);
      num[i].w += __shfl_xor(num[i].w, m);
    }
  }

  if (c == 0) {
#pragma unroll
    for (int i = 0; i < 4; ++i) {
      const float inv = 1.f / den[i];
      float* yp = y + ((size_t)(b * SQ + q0 + i)) * EE + h * DK;
      *reinterpret_cast<float4*>(yp) = make_float4(
          num[i].x * inv, num[i].y * inv, num[i].z * inv, num[i].w * inv);
    }
  }
}

// Kernel 2: out[t,e] = bias[e] + sum_j y[t,j] * W[e,j]  (4096 x 64 x 64).
// grid = 4096/16 = 256 blocks, 256 threads. W staged transposed in LDS.
__global__ __launch_bounds__(256) void proj_kernel(
    const float* __restrict__ y, const float* __restrict__ W,
    const float* __restrict__ bias, float* __restrict__ out) {
  const int tid = threadIdx.x;
  __shared__ float Wt[EE][EE + 1];   // +1 pad: conflict-free transpose write
  __shared__ float yt[16][EE];

  // Stage W via float4 global loads (1024 float4s; 4 per thread).
  const float4* W4 = reinterpret_cast<const float4*>(W);
#pragma unroll
  for (int k = 0; k < 4; ++k) {
    const int i4 = tid + k * 256;      // float4 index into W
    const float4 w = W4[i4];
    const int e = i4 >> 4;             // W row (output col)
    const int j = (i4 & 15) * 4;       // W col (input dim)
    Wt[j + 0][e] = w.x; Wt[j + 1][e] = w.y;
    Wt[j + 2][e] = w.z; Wt[j + 3][e] = w.w;
  }
  const size_t tok0 = (size_t)blockIdx.x * 16;
  {
    const float4 v = reinterpret_cast<const float4*>(y + tok0 * EE)[tid];
    *reinterpret_cast<float4*>(&yt[tid >> 4][(tid & 15) * 4]) = v;
  }
  __syncthreads();

  const int e = tid & 63;            // output column (coalesced stores)
  const int t0 = tid >> 6;           // 0..3; tokens t0, t0+4, t0+8, t0+12
  const float bv = bias[e];
  float acc[4] = {bv, bv, bv, bv};
#pragma unroll
  for (int j = 0; j < EE; ++j) {
    const float w = Wt[j][e];        // consecutive e -> conflict-free
#pragma unroll
    for (int k = 0; k < 4; ++k) acc[k] += yt[t0 + 4 * k][j] * w;  // broadcast
  }
#pragma unroll
  for (int k = 0; k < 4; ++k) {
    out[(tok0 + t0 + 4 * k) * EE + e] = acc[k];
  }
}

extern "C" void kernel_launch(void* const* d_in, const int* in_sizes, int n_in,
                              void* d_out, int out_size, void* d_ws, size_t ws_size,
                              hipStream_t stream) {
  const float* x     = (const float*)d_in[0];
  const float* theta = (const float*)d_in[1];
  const float* W     = (const float*)d_in[2];
  const float* bias  = (const float*)d_in[3];
  float* out = (float*)d_out;
  float* y   = (float*)d_ws;  // [B,S,E] fp32 = 1 MB attention output

  // PROBE: each kernel twice (idempotent; output identical).
  qattn_kernel<<<256, 512, 0, stream>>>(x, theta, y);
  qattn_kernel<<<256, 512, 0, stream>>>(x, theta, y);
  proj_kernel<<<256, 256, 0, stream>>>(y, W, bias, out);
  proj_kernel<<<256, 256, 0, stream>>>(y, W, bias, out);
}

// Round 6
// 19.203 us; speedup vs baseline: 3.0611x; 3.0611x over previous
//
#include <hip/hip_runtime.h>
#include <hip/hip_bf16.h>

#define SQ 1024
#define HH 16
#define DK 4
#define EE 64

using short8 = __attribute__((ext_vector_type(8))) short;
using f32x4  = __attribute__((ext_vector_type(4))) float;
using us4    = __attribute__((ext_vector_type(4))) unsigned short;
using us8    = __attribute__((ext_vector_type(8))) unsigned short;

static __device__ inline unsigned short f2bf(float f) {
  return __builtin_bit_cast(unsigned short, __float2bfloat16(f));
}

// MFMA flash attention. grid = 64 bh x 4 quarters = 256 blocks, 512 threads
// (8 waves). Wave w handles q-tiles {w*32, w*32+16} of the block's 256
// queries. Swapped QK^T (A = K-tokens) with permuted token->row assignment:
//   mfma1 row i <- token 8*(i>>2)+(i&3), mfma2 row i <- +4
// so D (col=lane&15=q, row=4h+r) == PV A-frag layout (k=8h+j). Shuffle-free.
// V gets a ones-column at n=4 -> den accumulates in acc col 4.
__global__ __launch_bounds__(512) void qattn_mfma(
    const float* __restrict__ x, const float* __restrict__ theta,
    float* __restrict__ y) {
  const int tid = threadIdx.x;
  const int quarter = blockIdx.x & 3;
  const int bh = blockIdx.x >> 2;
  const int hd = bh & (HH - 1);
  const int b = bh >> 4;

  // afrag[c][i]: 16B = {tokA(i) 4 bf16, tokB(i) 4 bf16}, tokA=8*(i>>2)+(i&3)
  __shared__ __align__(16) unsigned short afrag[32][16][8];   // 8 KB
  // vfrag[c][h][n][j] = V[32c+8h+j][n] bf16; n==4 slot = 1.0
  __shared__ __align__(16) unsigned short vfrag[32][4][5][8]; // 10 KB
  __shared__ __align__(16) unsigned short qfrag[256][4];      // 2 KB, scaled
  __shared__ __align__(16) unsigned short zslot[8];           // zeros

  const float4 th = *reinterpret_cast<const float4*>(theta);
  const float ct[4] = {__cosf(th.x), __cosf(th.y), __cosf(th.z), __cosf(th.w)};
  const float sc = 0.5f * 1.4426950408889634f;  // fold softmax scale + log2e
  const int q_lo = quarter * 256;

  if (tid < 8) zslot[tid] = 0;
#pragma unroll
  for (int k = 0; k < 2; ++k) {  // ones column (1024 entries)
    const int e = tid + k * 512;
    vfrag[e >> 5][(e >> 3) & 3][4][e & 7] = 0x3F80;
  }

  // Stage: proj = cos(x)*cos(theta), packed as bf16 fragments.
  const float* xb = x + ((size_t)b * SQ) * EE + hd * DK;
#pragma unroll
  for (int k = 0; k < 2; ++k) {
    const int t = tid + k * 512;
    const float4 v = *reinterpret_cast<const float4*>(xb + (size_t)t * EE);
    const float p[4] = {__cosf(v.x) * ct[0], __cosf(v.y) * ct[1],
                        __cosf(v.z) * ct[2], __cosf(v.w) * ct[3]};
    unsigned short pb[4], qb[4];
#pragma unroll
    for (int d = 0; d < 4; ++d) {
      pb[d] = f2bf(p[d]);
      qb[d] = f2bf(p[d] * sc);
    }
    const int c = t >> 5, tl = t & 31, hq = tl >> 3, j = tl & 7;
    *reinterpret_cast<us4*>(&afrag[c][4 * hq + (j & 3)][(j >= 4) ? 4 : 0]) =
        (us4){pb[0], pb[1], pb[2], pb[3]};
#pragma unroll
    for (int n = 0; n < 4; ++n) vfrag[c][hq][n][j] = pb[n];
    const int ql = t - q_lo;
    if ((unsigned)ql < 256u)
      *reinterpret_cast<us4*>(&qfrag[ql][0]) = (us4){qb[0], qb[1], qb[2], qb[3]};
  }
  __syncthreads();

  const int lane = tid & 63;
  const int wid = tid >> 6;
  const int n = lane & 15, hg = lane >> 4;

  // Q fragments (B-operand): lanes<16 carry d=0..3, rest zero.
  short8 qfA = {0, 0, 0, 0, 0, 0, 0, 0}, qfB = qfA;
  {
    const unsigned short* qa = (lane < 16) ? &qfrag[wid * 32 + n][0] : &zslot[0];
    const unsigned short* qb2 = (lane < 16) ? &qfrag[wid * 32 + 16 + n][0] : &zslot[0];
    const us4 ta = *reinterpret_cast<const us4*>(qa);
    const us4 tb = *reinterpret_cast<const us4*>(qb2);
#pragma unroll
    for (int i = 0; i < 4; ++i) { qfA[i] = (short)ta[i]; qfB[i] = (short)tb[i]; }
  }

  const unsigned short* aptr = (lane < 16) ? &afrag[0][n][0] : &zslot[0];
  const int astep = (lane < 16) ? 128 : 0;  // ushorts per chunk
  const unsigned short* vptr = (n <= 4) ? &vfrag[0][hg][n][0] : &zslot[0];
  const int vstep = (n <= 4) ? 160 : 0;

  f32x4 accA = {0.f, 0.f, 0.f, 0.f}, accB = accA;
  const f32x4 zero = {0.f, 0.f, 0.f, 0.f};

#pragma unroll 2
  for (int c = 0; c < 32; ++c) {
    const us8 av = *reinterpret_cast<const us8*>(aptr + c * astep);
    const short8 A1 = {(short)av[0], (short)av[1], (short)av[2], (short)av[3],
                       0, 0, 0, 0};
    const short8 A2 = {(short)av[4], (short)av[5], (short)av[6], (short)av[7],
                       0, 0, 0, 0};
    const f32x4 s1A = __builtin_amdgcn_mfma_f32_16x16x32_bf16(A1, qfA, zero, 0, 0, 0);
    const f32x4 s2A = __builtin_amdgcn_mfma_f32_16x16x32_bf16(A2, qfA, zero, 0, 0, 0);
    const f32x4 s1B = __builtin_amdgcn_mfma_f32_16x16x32_bf16(A1, qfB, zero, 0, 0, 0);
    const f32x4 s2B = __builtin_amdgcn_mfma_f32_16x16x32_bf16(A2, qfB, zero, 0, 0, 0);

    short8 PA_A, PA_B;
#pragma unroll
    for (int r = 0; r < 4; ++r) {
      PA_A[r]     = (short)f2bf(__builtin_amdgcn_exp2f(s1A[r]));
      PA_A[r + 4] = (short)f2bf(__builtin_amdgcn_exp2f(s2A[r]));
      PA_B[r]     = (short)f2bf(__builtin_amdgcn_exp2f(s1B[r]));
      PA_B[r + 4] = (short)f2bf(__builtin_amdgcn_exp2f(s2B[r]));
    }

    const us8 vv = *reinterpret_cast<const us8*>(vptr + c * vstep);
    const short8 VB = __builtin_bit_cast(short8, vv);
    accA = __builtin_amdgcn_mfma_f32_16x16x32_bf16(PA_A, VB, accA, 0, 0, 0);
    accB = __builtin_amdgcn_mfma_f32_16x16x32_bf16(PA_B, VB, accB, 0, 0, 0);
  }

  // Epilogue: lane holds acc for q = qbase + 4*hg + r, col n (n==4 -> den).
#pragma unroll
  for (int half = 0; half < 2; ++half) {
    const f32x4 acc = half ? accB : accA;
    const int qbase = q_lo + wid * 32 + half * 16;
#pragma unroll
    for (int r = 0; r < 4; ++r) {
      const float den = __shfl(acc[r], (lane & 48) | 4, 64);
      const float val = acc[r] * (1.0f / den);
      if (n < 4) {
        y[((size_t)(b * SQ + qbase + 4 * hg + r)) * EE + hd * DK + n] = val;
      }
    }
  }
}

// Kernel 2: out[t,e] = bias[e] + sum_j y[t,j] * W[e,j]  (4096 x 64 x 64).
__global__ __launch_bounds__(256) void proj_kernel(
    const float* __restrict__ y, const float* __restrict__ W,
    const float* __restrict__ bias, float* __restrict__ out) {
  const int tid = threadIdx.x;
  __shared__ float Wt[EE][EE + 1];
  __shared__ float yt[16][EE];

  const float4* W4 = reinterpret_cast<const float4*>(W);
#pragma unroll
  for (int k = 0; k < 4; ++k) {
    const int i4 = tid + k * 256;
    const float4 w = W4[i4];
    const int e = i4 >> 4;
    const int j = (i4 & 15) * 4;
    Wt[j + 0][e] = w.x; Wt[j + 1][e] = w.y;
    Wt[j + 2][e] = w.z; Wt[j + 3][e] = w.w;
  }
  const size_t tok0 = (size_t)blockIdx.x * 16;
  {
    const float4 v = reinterpret_cast<const float4*>(y + tok0 * EE)[tid];
    *reinterpret_cast<float4*>(&yt[tid >> 4][(tid & 15) * 4]) = v;
  }
  __syncthreads();

  const int e = tid & 63;
  const int t0 = tid >> 6;
  const float bv = bias[e];
  float acc[4] = {bv, bv, bv, bv};
#pragma unroll
  for (int j = 0; j < EE; ++j) {
    const float w = Wt[j][e];
#pragma unroll
    for (int k = 0; k < 4; ++k) acc[k] += yt[t0 + 4 * k][j] * w;
  }
#pragma unroll
  for (int k = 0; k < 4; ++k) {
    out[(tok0 + t0 + 4 * k) * EE + e] = acc[k];
  }
}

extern "C" void kernel_launch(void* const* d_in, const int* in_sizes, int n_in,
                              void* d_out, int out_size, void* d_ws, size_t ws_size,
                              hipStream_t stream) {
  const float* x     = (const float*)d_in[0];
  const float* theta = (const float*)d_in[1];
  const float* W     = (const float*)d_in[2];
  const float* bias  = (const float*)d_in[3];
  float* out = (float*)d_out;
  float* y   = (float*)d_ws;  // [B,S,E] fp32 = 1 MB attention output

  qattn_mfma<<<256, 512, 0, stream>>>(x, theta, y);
  proj_kernel<<<256, 256, 0, stream>>>(y, W, bias, out);
}